// Round 11
// baseline (167.898 us; speedup 1.0000x reference)
//
#include <hip/hip_runtime.h>
#include <hip/hip_bf16.h>

#define N_NODES 50000
#define N_EDGES 800000
#define HEADS   4
#define NEG_SLOPE 0.2f
#define CAP     64                    // bucket row: 63 edge slots + count in slot 63
#define NT      ((N_NODES + 63) / 64)       // 782 row blocks
#define EPB     2048                  // edges per edge-block
#define NCHUNK  ((N_EDGES + EPB - 1) / EPB) // 391 edge chunks
#define NREG    391                   // regions of 128 nodes (dst>>7)
#define QCAP    2560                  // queue cap/region: mean 2046 + 11 sigma
#define NAGG    (N_NODES / 16)        // 3125 agg blocks (EXACT: 16*3125 = 50000)
#define INV_LN2 1.44269504088896340736f

typedef __attribute__((ext_vector_type(8))) _Float16 half8;  // 8 f16 (4 VGPRs)
typedef __attribute__((ext_vector_type(4))) float f32x4;     // MFMA acc
typedef __attribute__((ext_vector_type(8))) unsigned short u16x8; // 16B of f16 bits

template <typename T> __device__ __forceinline__ float cvt(T v);
template <> __device__ __forceinline__ float cvt<float>(float v) { return v; }
template <> __device__ __forceinline__ float cvt<__hip_bfloat16>(__hip_bfloat16 v) {
    return __bfloat162float(v);
}
__device__ __forceinline__ unsigned short f2h(float f) {     // f32 -> f16 bits (RNE)
    _Float16 h = (_Float16)f;
    return __builtin_bit_cast(unsigned short, h);
}
__device__ __forceinline__ float hbits(unsigned short u) {   // f16 bits -> f32
    return (float)__builtin_bit_cast(_Float16, u);           // folds into v_fma_mix
}
__device__ __forceinline__ int probe_fp32(const unsigned* xw) {
    int sane = 0;
    for (int j = 0; j < 64; ++j) {
        unsigned e = (xw[j] >> 7) & 0xFF;    // exponent of low half viewed as bf16
        sane += (e >= 90 && e <= 141);
    }
    return sane < 32;                        // junk low halves => fp32 buffer
}
__device__ __forceinline__ float loadW(int isf32, const void* W, int idx) {
    return isf32 ? ((const float*)W)[idx]
                 : cvt<__hip_bfloat16>(((const __hip_bfloat16*)W)[idx]);
}

// load 8 contiguous elems as f16, vectorized (b128 loads)
template <typename T>
__device__ __forceinline__ void load8_f16(const T* p, _Float16* dst);
template <>
__device__ __forceinline__ void load8_f16<float>(const float* p, _Float16* dst) {
    float4 a = *(const float4*)p;            // 32B-aligned (offsets are 8-float mult.)
    float4 b = *(const float4*)(p + 4);
    dst[0] = (_Float16)a.x; dst[1] = (_Float16)a.y;
    dst[2] = (_Float16)a.z; dst[3] = (_Float16)a.w;
    dst[4] = (_Float16)b.x; dst[5] = (_Float16)b.y;
    dst[6] = (_Float16)b.z; dst[7] = (_Float16)b.w;
}
template <>
__device__ __forceinline__ void load8_f16<__hip_bfloat16>(const __hip_bfloat16* p,
                                                          _Float16* dst) {
    uint4 a = *(const uint4*)p;              // 8 bf16 = 16B
    const unsigned short* u = (const unsigned short*)&a;
#pragma unroll
    for (int j = 0; j < 8; ++j)
        dst[j] = (_Float16)__uint_as_float(((unsigned)u[j]) << 16);
}

// ------------- fused init: probes + zero qcnt + pack Batt + Bpost -----------
// flags[0]: edge_index is int64. flags[1]: float inputs are fp32.
// Block 0: flags + zero qcnt. Block 1: att-fold Batt = (W @ a)/ln2 in MFMA-B
// layout. Blocks 2..5: Bpost = Wstack[256,64]/4 in MFMA-B layout, where
// Wstack[h*64+k, c] = W[k, h*64+c] (mean folded). B layout (HW-verified):
// within one K=32 MFMA, value(l,j)=B[k=(l>>4)*8+j][n=l&15].
__global__ __launch_bounds__(256) void k_init(const unsigned* __restrict__ xw,
                                              const int* __restrict__ ei,
                                              const void* __restrict__ W,
                                              const void* __restrict__ att_src,
                                              const void* __restrict__ att_dst,
                                              int* __restrict__ qcnt,
                                              int* __restrict__ flags,
                                              unsigned short* __restrict__ Batt,
                                              unsigned short* __restrict__ Bpost) {
    __shared__ float waS[256], waD[256];
    __shared__ int f32sh;
    if (blockIdx.x == 0) {
        for (int t = threadIdx.x; t < NREG; t += 256) qcnt[t] = 0;
        if (threadIdx.x == 0) {
            int all0 = 1;
            for (int j = 1; j < 64; j += 2) all0 &= (ei[j] == 0);
            flags[0] = all0;
            flags[1] = probe_fp32(xw);
        }
        return;
    }
    const int pb = blockIdx.x - 1;           // 0 = att fold, 1..4 = Bpost
    if (threadIdx.x == 0) f32sh = probe_fp32(xw);   // local probe (race-free)
    __syncthreads();
    const int isf32 = f32sh;
    if (pb == 0) {
        int t = threadIdx.x, k = t >> 2, h = t & 3;
        float s = 0.f, d = 0.f;
        for (int c = 0; c < 64; ++c) {
            float w = loadW(isf32, W, k * 256 + h * 64 + c);
            float as = isf32 ? ((const float*)att_src)[h * 64 + c]
                             : cvt<__hip_bfloat16>(((const __hip_bfloat16*)att_src)[h * 64 + c]);
            float ad = isf32 ? ((const float*)att_dst)[h * 64 + c]
                             : cvt<__hip_bfloat16>(((const __hip_bfloat16*)att_dst)[h * 64 + c]);
            s = fmaf(w, as, s);
            d = fmaf(w, ad, d);
        }
        waS[t] = s * INV_LN2;
        waD[t] = d * INV_LN2;
        __syncthreads();
        if (threadIdx.x < 128) {
            int r = threadIdx.x;             // r = q*64 + l, q = K-half
            int q = (r >> 6) & 1, l = r & 63, n = l & 15;
            int kbase = q * 32 + ((l >> 4) & 3) * 8;
#pragma unroll
            for (int j = 0; j < 8; ++j) {
                int kk = kbase + j;
                float v = (n < 4) ? waS[kk * 4 + n]
                        : (n < 8) ? waD[kk * 4 + (n - 4)] : 0.f;
                Batt[r * 8 + j] = f2h(v);
            }
        }
    } else {
        // Bpost: tile t = kt*4+nt (t = 0..31); this block packs 8 tiles.
        const int sub = threadIdx.x >> 5, s = threadIdx.x & 31;
        const int t = (pb - 1) * 8 + sub;
        const int kt = t >> 2, nt = t & 3;
#pragma unroll
        for (int e = 0; e < 16; ++e) {
            int idx = s * 16 + e;            // 0..511 within tile
            int l = idx >> 3, j = idx & 7;
            int rs = kt * 32 + ((l >> 4) & 3) * 8 + j;   // row of Wstack (0..255)
            int h = rs >> 6, k_in = rs & 63;
            int c = nt * 16 + (l & 15);
            Bpost[t * 512 + l * 8 + j] =
                f2h(loadW(isf32, W, k_in * 256 + h * 64 + c) * 0.25f);
        }
    }
}

// ---------------- logits + x->f16 from MFMA afrags (all k_mid blocks) --------
// Block = 64 rows, 4 waves; wave w: rows 16w..16w+15; single n-tile (Batt).
// C layout (HW-verified): col=lane&15, row=quad*4+reg. Cols 0..3 = a_src heads,
// 4..7 = a_dst heads (1/ln2-scaled) -> direct fp32 global writes.
// x16 is stored FROM the already-converted afrag registers.
template <typename T>
__device__ __forceinline__ void row_body(const T* __restrict__ x,
                                         const unsigned short* __restrict__ Batt,
                                         unsigned short* __restrict__ x16,
                                         float* __restrict__ a_src,
                                         float* __restrict__ a_dst) {
    const int tid = threadIdx.x;
    const int wav = tid >> 6, lane = tid & 63;
    const int quad = lane >> 4, r15 = lane & 15;
    const int m0 = blockIdx.x * 64;
    const int grow_a = m0 + wav * 16 + r15;     // this lane's A row (m = lane&15)
    int gr = grow_a;
    if (gr >= N_NODES) gr = N_NODES - 1;        // clamp; stores guarded
    half8 afrag[2];
#pragma unroll
    for (int q = 0; q < 2; ++q) {
        _Float16 tmp[8];
        load8_f16<T>(x + (size_t)gr * 64 + q * 32 + quad * 8, tmp);
#pragma unroll
        for (int j = 0; j < 8; ++j) afrag[q][j] = tmp[j];
    }
    // ---- f16 copy of x straight from registers (16B per store, full lines) -
    if (grow_a < N_NODES) {
#pragma unroll
        for (int q = 0; q < 2; ++q)
            *(half8*)(x16 + (size_t)grow_a * 64 + q * 32 + quad * 8) = afrag[q];
    }
    f32x4 acc = (f32x4){0.f, 0.f, 0.f, 0.f};
    const half8* bp = (const half8*)Batt;
    acc = __builtin_amdgcn_mfma_f32_16x16x32_f16(afrag[0], bp[lane], acc, 0, 0, 0);
    acc = __builtin_amdgcn_mfma_f32_16x16x32_f16(afrag[1], bp[64 + lane], acc, 0, 0, 0);
    if (r15 < 8) {
#pragma unroll
        for (int r = 0; r < 4; ++r) {
            int grow = m0 + wav * 16 + quad * 4 + r;
            if (grow < N_NODES) {
                if (r15 < 4) a_src[grow * HEADS + r15]       = acc[r];
                else         a_dst[grow * HEADS + (r15 - 4)] = acc[r];
            }
        }
    }
}

// ---------------- fused mid: rows + REGION-BUCKETED edge append -------------
// Even blocks bucket EPB=2048 edges into 391 region queues (region = dst>>7)
// as packed 4B records. Edge loads PAIRED (int4/int2) for full-line use.
// Global atomics ~150K (one per block x region), issued before row_body so
// the round trip hides under it.
__global__ __launch_bounds__(256) void k_mid(const void* __restrict__ x,
                                             const unsigned short* __restrict__ Batt,
                                             const int* __restrict__ ei,
                                             const int* __restrict__ flags,
                                             int* __restrict__ qcnt,
                                             unsigned* __restrict__ queue,
                                             unsigned short* __restrict__ x16,
                                             float* __restrict__ a_src,
                                             float* __restrict__ a_dst) {
    __shared__ int hist[NREG];
    __shared__ int qbaseS[NREG];
    const int tid = threadIdx.x;
    const bool edge_blk = ((blockIdx.x & 1) == 0);   // interleaved for CU balance
    const int eb = blockIdx.x >> 1;                  // 0..390
    unsigned rec[8]; int reg[8], lpos[8];
    int histv0 = 0, histv1 = 0, mybase0 = 0, mybase1 = 0;
    if (edge_blk) {
        for (int t = tid; t < NREG; t += 256) hist[t] = 0;
        __syncthreads();
        const int f64 = flags[0];
        const int pbase = eb * 1024 + tid;           // pair index (2 edges/pair)
#pragma unroll
        for (int k = 0; k < 4; ++k) {
            int pid = pbase + k * 256;
            int e = 2 * pid;
            if (e < N_EDGES) {                       // N_EDGES even => e+1 valid
                int s0, d0, s1, d1;
                if (f64) {                           // 16B = 2 int64 edges
                    int4 sv = *(const int4*)(ei + 2 * e);
                    int4 dv = *(const int4*)(ei + 2 * N_EDGES + 2 * e);
                    s0 = sv.x; s1 = sv.z; d0 = dv.x; d1 = dv.z;
                } else {                             // 8B = 2 int32 edges
                    int2 sv = *(const int2*)(ei + e);
                    int2 dv = *(const int2*)(ei + N_EDGES + e);
                    s0 = sv.x; s1 = sv.y; d0 = dv.x; d1 = dv.y;
                }
                reg[2 * k]     = d0 >> 7;
                rec[2 * k]     = (unsigned)s0 | ((unsigned)d0 << 16);
                reg[2 * k + 1] = d1 >> 7;
                rec[2 * k + 1] = (unsigned)s1 | ((unsigned)d1 << 16);
            } else { reg[2 * k] = -1; reg[2 * k + 1] = -1; }
        }
#pragma unroll
        for (int k = 0; k < 8; ++k)
            if (reg[k] >= 0) lpos[k] = atomicAdd(&hist[reg[k]], 1);
        __syncthreads();
        {   // qcnt atomics issued BEFORE row_body (round trip hides under it)
            int t0 = tid, t1 = tid + 256;
            histv0 = hist[t0];
            if (histv0) mybase0 = atomicAdd(qcnt + t0, histv0);
            if (t1 < NREG) {
                histv1 = hist[t1];
                if (histv1) mybase1 = atomicAdd(qcnt + t1, histv1);
            }
        }
    }
    // ---- rows for ALL blocks ----
    if (flags[1]) row_body<float>((const float*)x, Batt, x16, a_src, a_dst);
    else          row_body<__hip_bfloat16>((const __hip_bfloat16*)x, Batt,
                                           x16, a_src, a_dst);
    if (edge_blk) {
        qbaseS[tid] = mybase0;
        if (tid + 256 < NREG) qbaseS[tid + 256] = mybase1;
        __syncthreads();
#pragma unroll
        for (int k = 0; k < 8; ++k)
            if (reg[k] >= 0) {
                int o = qbaseS[reg[k]] + lpos[k];
                if (o < QCAP)
                    queue[(size_t)reg[k] * QCAP + o] = rec[k];
            }
    }
}

// ---------------- scat: per-region queue -> col_pad (L2-local) --------------
// One block per 128-node region (16 KB col_pad window, single-XCD L2).
// Positions via LDS atomics. Per-node count stored IN col_pad slot 63
// (self-loop occupies lane n <= 63, so slot 63 is never an edge slot).
__global__ __launch_bounds__(256) void k_scat(const unsigned* __restrict__ queue,
                                              const int* __restrict__ qcnt,
                                              unsigned short* __restrict__ col_pad) {
    __shared__ int cl[128];
    const int b = blockIdx.x, tid = threadIdx.x;
    const int base = b << 7;
    if (tid < 128) cl[tid] = 0;
    __syncthreads();
    int m = qcnt[b]; m = m > QCAP ? QCAP : m;
    const unsigned* q = queue + (size_t)b * QCAP;
    for (int i = tid; i < m; i += 256) {
        unsigned rec = q[i];
        int d = rec >> 16, s = rec & 0xffff;
        int p = atomicAdd(&cl[d - base], 1);
        if (p < CAP - 1) col_pad[(size_t)d * CAP + p] = (unsigned short)s;
    }
    __syncthreads();
    if (tid < 128) {
        int j = base + tid;
        if (j < N_NODES) {
            int c = cl[tid]; c = c > CAP - 1 ? CAP - 1 : c;
            col_pad[(size_t)j * CAP + (CAP - 1)] = (unsigned short)c;
        }
    }
}

// 2-dim x 4-head accumulate for one edge's dword; a[8] const-indexed (regs)
__device__ __forceinline__ void acc2(unsigned D, float4 P, float* a, float* sp) {
    float x0 = hbits((unsigned short)(D & 0xffff));
    float x1 = hbits((unsigned short)(D >> 16));
    a[0] = fmaf(P.x, x0, a[0]); a[1] = fmaf(P.x, x1, a[1]);
    a[2] = fmaf(P.y, x0, a[2]); a[3] = fmaf(P.y, x1, a[3]);
    a[4] = fmaf(P.z, x0, a[4]); a[5] = fmaf(P.z, x1, a[5]);
    a[6] = fmaf(P.w, x0, a[6]); a[7] = fmaf(P.w, x1, a[7]);
    sp[0] += P.x; sp[1] += P.y; sp[2] += P.z; sp[3] += P.w;
}

// -------- fused aggregate+post v4: NODE-PAIR interleaved gather (MLP x2) ----
// R10 post-mortem: unroll-8 on one chain ~nil (44.7us) -> the per-round chain
// (ds_read cols -> gather -> consume) re-serializes; single chain per wave
// exposes ~560cy/round. v4: process the wave's 4 nodes as 2 PAIRS, gathering
// both nodes' rounds interleaved — two independent LDS lists + accumulators +
// global streams = true MLP x2 without deepening any chain. Prologues pair up
// too. Cost: 2x acc regs (~90 VGPR), peS/cS doubled (LDS 18.7KB). Staging,
// phase 2, f2h numerics identical to R8/R10.
template <typename T>
__device__ __forceinline__ void agg_body(const unsigned short* __restrict__ col_pad,
                                         const float* __restrict__ a_src,
                                         const float* __restrict__ a_dst,
                                         const unsigned short* __restrict__ x16,
                                         const unsigned short* __restrict__ Bpost,
                                         const T* __restrict__ bias,
                                         const T* __restrict__ fc_w,
                                         const T* __restrict__ fc_b,
                                         float* __restrict__ out,
                                         int* __restrict__ cS,
                                         float4* __restrict__ peS,
                                         unsigned* __restrict__ sS,
                                         float* __restrict__ postS) {
    const int tid = threadIdx.x;
    const int wav = tid >> 6, lane = tid & 63;
    const int hlf = lane >> 5, l5 = lane & 31;
    const int quad = lane >> 4, r15 = lane & 15;
    const int nbase = blockIdx.x * 16 + wav * 4;            // 4 nodes/wave, 2 pairs
    int*    cA_ = cS  + (wav * 2 + 0) * 64;
    int*    cB_ = cS  + (wav * 2 + 1) * 64;
    float4* pA_ = peS + (wav * 2 + 0) * 64;
    float4* pB_ = peS + (wav * 2 + 1) * 64;
    const int slot = (lane & 1) * 32 + (lane >> 1);         // parity interleave
    const char* xb = (const char*)x16 + l5 * 4;             // my dim-pair slice
    int cvalA = (int)col_pad[(size_t)nbase * CAP + lane];         // node 0 row
    int cvalB = (int)col_pad[(size_t)(nbase + 1) * CAP + lane];   // node 1 row
#pragma unroll
    for (int pr = 0; pr < 2; ++pr) {
        const int widA = nbase + pr * 2, widB = widA + 1;
        int cvalA2 = 0, cvalB2 = 0;
        if (pr == 0) {                                      // prefetch pair 1 rows
            cvalA2 = (int)col_pad[(size_t)(nbase + 2) * CAP + lane];
            cvalB2 = (int)col_pad[(size_t)(nbase + 3) * CAP + lane];
        }
        const int nA = __shfl(cvalA, 63, 64);               // counts from slot 63
        const int nB = __shfl(cvalB, 63, 64);
        const float4 adA = ((const float4*)a_dst)[widA];    // uniform
        const float4 adB = ((const float4*)a_dst)[widB];
        const int mcA = (lane < nA) ? cvalA : widA;         // lane n = self loop
        const int mcB = (lane < nB) ? cvalB : widB;
        const float4 asA = ((const float4*)a_src)[mcA];     // two indep. chains
        const float4 asB = ((const float4*)a_src)[mcB];
        float4 peA, peB;
        {
            float e0 = asA.x + adA.x, e1 = asA.y + adA.y;
            float e2 = asA.z + adA.z, e3 = asA.w + adA.w;
            e0 = e0 > 0.f ? e0 : NEG_SLOPE * e0;  e1 = e1 > 0.f ? e1 : NEG_SLOPE * e1;
            e2 = e2 > 0.f ? e2 : NEG_SLOPE * e2;  e3 = e3 > 0.f ? e3 : NEG_SLOPE * e3;
            peA = make_float4(exp2f(e0), exp2f(e1), exp2f(e2), exp2f(e3));
            if (lane > nA) peA = make_float4(0.f, 0.f, 0.f, 0.f);
        }
        {
            float e0 = asB.x + adB.x, e1 = asB.y + adB.y;
            float e2 = asB.z + adB.z, e3 = asB.w + adB.w;
            e0 = e0 > 0.f ? e0 : NEG_SLOPE * e0;  e1 = e1 > 0.f ? e1 : NEG_SLOPE * e1;
            e2 = e2 > 0.f ? e2 : NEG_SLOPE * e2;  e3 = e3 > 0.f ? e3 : NEG_SLOPE * e3;
            peB = make_float4(exp2f(e0), exp2f(e1), exp2f(e2), exp2f(e3));
            if (lane > nB) peB = make_float4(0.f, 0.f, 0.f, 0.f);
        }
        cA_[slot] = mcA << 7;  pA_[slot] = peA;             // x16 row BYTE offsets
        cB_[slot] = mcB << 7;  pB_[slot] = peB;             // wave-sync (in-order DS)
        // ---- interleaved gather: round r covers edge 2r+hlf of BOTH nodes --
        float aA[8] = {0,0,0,0,0,0,0,0}, aB[8] = {0,0,0,0,0,0,0,0};
        float spA[4] = {0,0,0,0},        spB[4] = {0,0,0,0};
        const int nrA = (nA + 2) >> 1, nrB = (nB + 2) >> 1;
        const int rmin = nrA < nrB ? nrA : nrB;
        const int*    ccA = cA_ + hlf * 32;
        const float4* ppA = pA_ + hlf * 32;
        const int*    ccB = cB_ + hlf * 32;
        const float4* ppB = pB_ + hlf * 32;
        int r = 0;
        for (; r + 4 <= rmin; r += 4) {                     // 8 loads in flight
            const int4 iA = *(const int4*)(ccA + r);
            const int4 iB = *(const int4*)(ccB + r);
            unsigned dA0 = *(const unsigned*)(xb + iA.x);
            unsigned dB0 = *(const unsigned*)(xb + iB.x);
            unsigned dA1 = *(const unsigned*)(xb + iA.y);
            unsigned dB1 = *(const unsigned*)(xb + iB.y);
            unsigned dA2 = *(const unsigned*)(xb + iA.z);
            unsigned dB2 = *(const unsigned*)(xb + iB.z);
            unsigned dA3 = *(const unsigned*)(xb + iA.w);
            unsigned dB3 = *(const unsigned*)(xb + iB.w);
            float4 qA0 = ppA[r],     qB0 = ppB[r];
            float4 qA1 = ppA[r + 1], qB1 = ppB[r + 1];
            float4 qA2 = ppA[r + 2], qB2 = ppB[r + 2];
            float4 qA3 = ppA[r + 3], qB3 = ppB[r + 3];
            acc2(dA0, qA0, aA, spA); acc2(dB0, qB0, aB, spB);
            acc2(dA1, qA1, aA, spA); acc2(dB1, qB1, aB, spB);
            acc2(dA2, qA2, aA, spA); acc2(dB2, qB2, aB, spB);
            acc2(dA3, qA3, aA, spA); acc2(dB3, qB3, aB, spB);
        }
        for (; r < rmin; ++r) {
            unsigned dA = *(const unsigned*)(xb + ccA[r]);
            unsigned dB = *(const unsigned*)(xb + ccB[r]);
            float4 qA = ppA[r], qB = ppB[r];
            acc2(dA, qA, aA, spA); acc2(dB, qB, aB, spB);
        }
        for (; r < nrA; ++r) {                              // A tail
            unsigned d = *(const unsigned*)(xb + ccA[r]);
            float4 q = ppA[r];
            acc2(d, q, aA, spA);
        }
        for (; r < nrB; ++r) {                              // B tail
            unsigned d = *(const unsigned*)(xb + ccB[r]);
            float4 q = ppB[r];
            acc2(d, q, aB, spB);
        }
        // ---- fold the two 32-lane halves (same dims, disjoint edges) -------
#pragma unroll
        for (int k = 0; k < 8; ++k) {
            aA[k] += __shfl_xor(aA[k], 32, 64);
            aB[k] += __shfl_xor(aB[k], 32, 64);
        }
#pragma unroll
        for (int k = 0; k < 4; ++k) {
            spA[k] += __shfl_xor(spA[k], 32, 64);
            spB[k] += __shfl_xor(spB[k], 32, 64);
        }
        // ---- normalize + stage both rows into LDS (identical f2h packing) --
        if (lane < 32) {
            const float rA0 = 1.f / spA[0], rA1 = 1.f / spA[1];
            const float rA2 = 1.f / spA[2], rA3 = 1.f / spA[3];
            unsigned* sr = sS + (wav * 4 + pr * 2) * 132;   // pitch 132 dwords
            sr[l5]      = (unsigned)f2h(aA[0] * rA0) | ((unsigned)f2h(aA[1] * rA0) << 16);
            sr[32 + l5] = (unsigned)f2h(aA[2] * rA1) | ((unsigned)f2h(aA[3] * rA1) << 16);
            sr[64 + l5] = (unsigned)f2h(aA[4] * rA2) | ((unsigned)f2h(aA[5] * rA2) << 16);
            sr[96 + l5] = (unsigned)f2h(aA[6] * rA3) | ((unsigned)f2h(aA[7] * rA3) << 16);
            const float rB0 = 1.f / spB[0], rB1 = 1.f / spB[1];
            const float rB2 = 1.f / spB[2], rB3 = 1.f / spB[3];
            unsigned* sr2 = sr + 132;
            sr2[l5]      = (unsigned)f2h(aB[0] * rB0) | ((unsigned)f2h(aB[1] * rB0) << 16);
            sr2[32 + l5] = (unsigned)f2h(aB[2] * rB1) | ((unsigned)f2h(aB[3] * rB1) << 16);
            sr2[64 + l5] = (unsigned)f2h(aB[4] * rB2) | ((unsigned)f2h(aB[5] * rB2) << 16);
            sr2[96 + l5] = (unsigned)f2h(aB[6] * rB3) | ((unsigned)f2h(aB[7] * rB3) << 16);
        }
        cvalA = cvalA2; cvalB = cvalB2;
    }
    __syncthreads();
    // ---- post phase: ALL 4 waves, wave = n-tile nt --------------------------
    {
        const int nt = wav;
        f32x4 acc = (f32x4){0.f, 0.f, 0.f, 0.f};
        const half8* bp = (const half8*)Bpost;
#pragma unroll
        for (int kt = 0; kt < 8; ++kt) {
            half8 af = *(const half8*)&sS[r15 * 132 + kt * 16 + quad * 4];
            acc = __builtin_amdgcn_mfma_f32_16x16x32_f16(
                af, bp[(kt * 4 + nt) * 64 + lane], acc, 0, 0, 0);
        }
        const float bi = cvt<T>(bias[nt * 16 + r15]);
        const float fw = cvt<T>(fc_w[nt * 16 + r15]);
#pragma unroll
        for (int rr = 0; rr < 4; ++rr) {
            float o = acc[rr] + bi;
            o = o > 0.f ? o : 0.f;              // relu
            float p = o * fw;
            p += __shfl_xor(p, 1, 64); p += __shfl_xor(p, 2, 64);
            p += __shfl_xor(p, 4, 64); p += __shfl_xor(p, 8, 64);
            if (r15 == 0) postS[(quad * 4 + rr) * 4 + nt] = p;
        }
    }
    __syncthreads();
    if (tid < 16) {
        float o = postS[tid * 4] + postS[tid * 4 + 1]
                + postS[tid * 4 + 2] + postS[tid * 4 + 3] + cvt<T>(fc_b[0]);
        out[blockIdx.x * 16 + tid] = o;
    }
}

__global__ __launch_bounds__(256) void k_aggregate(
        const unsigned short* __restrict__ col_pad,
        const float* __restrict__ a_src,
        const float* __restrict__ a_dst,
        const unsigned short* __restrict__ x16,
        const unsigned short* __restrict__ Bpost,
        const void* __restrict__ bias,
        const void* __restrict__ fc_w,
        const void* __restrict__ fc_b,
        const int* __restrict__ flags,
        float* __restrict__ out) {
    __shared__ __align__(16) int cS[4 * 2 * 64];    // per-wave A/B col lists
    __shared__ float4 peS[4 * 2 * 64];
    __shared__ __align__(16) unsigned sS[16 * 132];  // staged s rows (f16 pairs)
    __shared__ float postS[16 * 4];
    if (flags[1])
        agg_body<float>(col_pad, a_src, a_dst, x16, Bpost, (const float*)bias,
                        (const float*)fc_w, (const float*)fc_b, out,
                        cS, peS, sS, postS);
    else
        agg_body<__hip_bfloat16>(col_pad, a_src, a_dst, x16, Bpost,
                                 (const __hip_bfloat16*)bias,
                                 (const __hip_bfloat16*)fc_w,
                                 (const __hip_bfloat16*)fc_b, out,
                                 cS, peS, sS, postS);
}

extern "C" void kernel_launch(void* const* d_in, const int* in_sizes, int n_in,
                              void* d_out, int out_size, void* d_ws, size_t ws_size,
                              hipStream_t stream) {
    const void* x       = d_in[0];
    const int*  ei      = (const int*)d_in[1];
    const void* W       = d_in[2];
    const void* att_src = d_in[3];
    const void* att_dst = d_in[4];
    const void* bias    = d_in[5];
    const void* fc_w    = d_in[6];
    const void* fc_b    = d_in[7];
    float* out = (float*)d_out;

    char* wsb = (char*)d_ws;                                      // ~18.4 MB total
    unsigned short* x16   = (unsigned short*)wsb;                 // 6.4 MB (f16 x)
    unsigned*       queue = (unsigned*)(wsb + 6400000);           // 4.0 MB
    unsigned short* col_pad = (unsigned short*)(wsb + 10403840);  // 6.4 MB (128B-align)
    float* a_src = (float*)(wsb + 16803840);                      // 800 KB
    float* a_dst = (float*)(wsb + 17603840);                      // 800 KB
    unsigned short* Batt  = (unsigned short*)(wsb + 18403840);    // 2 KB
    unsigned short* Bpost = (unsigned short*)(wsb + 18405888);    // 32 KB
    int* flags = (int*)(wsb + 18438656);                          // 8 B
    int* qcnt  = (int*)(wsb + 18438664);                          // 1.6 KB

    k_init<<<6, 256, 0, stream>>>((const unsigned*)x, ei, W, att_src,
                                  att_dst, qcnt, flags, Batt, Bpost);
    k_mid<<<NT, 256, 0, stream>>>(x, Batt, ei, flags, qcnt, queue,
                                  x16, a_src, a_dst);
    k_scat<<<NREG, 256, 0, stream>>>(queue, qcnt, col_pad);
    k_aggregate<<<NAGG, 256, 0, stream>>>(col_pad, a_src, a_dst, x16, Bpost,
                                          bias, fc_w, fc_b, flags, out);
}

// Round 12
// 156.234 us; speedup vs baseline: 1.0747x; 1.0747x over previous
//
#include <hip/hip_runtime.h>
#include <hip/hip_bf16.h>

#define N_NODES 50000
#define N_EDGES 800000
#define HEADS   4
#define NEG_SLOPE 0.2f
#define CAP     64                    // bucket row: 63 edge slots + count in slot 63
#define NT      ((N_NODES + 63) / 64)       // 782 row blocks
#define EPB     2048                  // edges per edge-block
#define NREG    391                   // regions of 128 nodes (dst>>7)
#define NREP    8                     // qcnt replicas (kills same-addr atomic chain)
#define QSUB    384                   // sub-queue cap: mean 256 + 8 sigma
#define NAGG    (N_NODES / 16)        // 3125 agg blocks (EXACT: 16*3125 = 50000)
#define INV_LN2 1.44269504088896340736f

typedef __attribute__((ext_vector_type(8))) _Float16 half8;  // 8 f16 (4 VGPRs)
typedef __attribute__((ext_vector_type(4))) float f32x4;     // MFMA acc
typedef __attribute__((ext_vector_type(8))) unsigned short u16x8; // 16B of f16 bits

template <typename T> __device__ __forceinline__ float cvt(T v);
template <> __device__ __forceinline__ float cvt<float>(float v) { return v; }
template <> __device__ __forceinline__ float cvt<__hip_bfloat16>(__hip_bfloat16 v) {
    return __bfloat162float(v);
}
__device__ __forceinline__ unsigned short f2h(float f) {     // f32 -> f16 bits (RNE)
    _Float16 h = (_Float16)f;
    return __builtin_bit_cast(unsigned short, h);
}
__device__ __forceinline__ float hbits(unsigned short u) {   // f16 bits -> f32
    return (float)__builtin_bit_cast(_Float16, u);           // folds into v_fma_mix
}
__device__ __forceinline__ int probe_fp32(const unsigned* xw) {
    int sane = 0;
    for (int j = 0; j < 64; ++j) {
        unsigned e = (xw[j] >> 7) & 0xFF;    // exponent of low half viewed as bf16
        sane += (e >= 90 && e <= 141);
    }
    return sane < 32;                        // junk low halves => fp32 buffer
}
__device__ __forceinline__ float loadW(int isf32, const void* W, int idx) {
    return isf32 ? ((const float*)W)[idx]
                 : cvt<__hip_bfloat16>(((const __hip_bfloat16*)W)[idx]);
}

// load 8 contiguous elems as f16, vectorized (b128 loads)
template <typename T>
__device__ __forceinline__ void load8_f16(const T* p, _Float16* dst);
template <>
__device__ __forceinline__ void load8_f16<float>(const float* p, _Float16* dst) {
    float4 a = *(const float4*)p;            // 32B-aligned (offsets are 8-float mult.)
    float4 b = *(const float4*)(p + 4);
    dst[0] = (_Float16)a.x; dst[1] = (_Float16)a.y;
    dst[2] = (_Float16)a.z; dst[3] = (_Float16)a.w;
    dst[4] = (_Float16)b.x; dst[5] = (_Float16)b.y;
    dst[6] = (_Float16)b.z; dst[7] = (_Float16)b.w;
}
template <>
__device__ __forceinline__ void load8_f16<__hip_bfloat16>(const __hip_bfloat16* p,
                                                          _Float16* dst) {
    uint4 a = *(const uint4*)p;              // 8 bf16 = 16B
    const unsigned short* u = (const unsigned short*)&a;
#pragma unroll
    for (int j = 0; j < 8; ++j)
        dst[j] = (_Float16)__uint_as_float(((unsigned)u[j]) << 16);
}

// ------------- fused init: probes + zero qcnt + pack Batt + Bpost -----------
// flags[0]: edge_index is int64. flags[1]: float inputs are fp32.
// Block 0: flags + zero qcnt (8 replicas). Block 1: att-fold Batt = (W @ a)/ln2
// in MFMA-B layout. Blocks 2..5: Bpost = Wstack[256,64]/4 in MFMA-B layout,
// Wstack[h*64+k, c] = W[k, h*64+c] (mean folded). B layout (HW-verified):
// within one K=32 MFMA, value(l,j)=B[k=(l>>4)*8+j][n=l&15].
__global__ __launch_bounds__(256) void k_init(const unsigned* __restrict__ xw,
                                              const int* __restrict__ ei,
                                              const void* __restrict__ W,
                                              const void* __restrict__ att_src,
                                              const void* __restrict__ att_dst,
                                              int* __restrict__ qcnt,
                                              int* __restrict__ flags,
                                              unsigned short* __restrict__ Batt,
                                              unsigned short* __restrict__ Bpost) {
    __shared__ float waS[256], waD[256];
    __shared__ int f32sh;
    if (blockIdx.x == 0) {
        for (int t = threadIdx.x; t < NREP * NREG; t += 256) qcnt[t] = 0;
        if (threadIdx.x == 0) {
            int all0 = 1;
            for (int j = 1; j < 64; j += 2) all0 &= (ei[j] == 0);
            flags[0] = all0;
            flags[1] = probe_fp32(xw);
        }
        return;
    }
    const int pb = blockIdx.x - 1;           // 0 = att fold, 1..4 = Bpost
    if (threadIdx.x == 0) f32sh = probe_fp32(xw);   // local probe (race-free)
    __syncthreads();
    const int isf32 = f32sh;
    if (pb == 0) {
        int t = threadIdx.x, k = t >> 2, h = t & 3;
        float s = 0.f, d = 0.f;
        for (int c = 0; c < 64; ++c) {
            float w = loadW(isf32, W, k * 256 + h * 64 + c);
            float as = isf32 ? ((const float*)att_src)[h * 64 + c]
                             : cvt<__hip_bfloat16>(((const __hip_bfloat16*)att_src)[h * 64 + c]);
            float ad = isf32 ? ((const float*)att_dst)[h * 64 + c]
                             : cvt<__hip_bfloat16>(((const __hip_bfloat16*)att_dst)[h * 64 + c]);
            s = fmaf(w, as, s);
            d = fmaf(w, ad, d);
        }
        waS[t] = s * INV_LN2;
        waD[t] = d * INV_LN2;
        __syncthreads();
        if (threadIdx.x < 128) {
            int r = threadIdx.x;             // r = q*64 + l, q = K-half
            int q = (r >> 6) & 1, l = r & 63, n = l & 15;
            int kbase = q * 32 + ((l >> 4) & 3) * 8;
#pragma unroll
            for (int j = 0; j < 8; ++j) {
                int kk = kbase + j;
                float v = (n < 4) ? waS[kk * 4 + n]
                        : (n < 8) ? waD[kk * 4 + (n - 4)] : 0.f;
                Batt[r * 8 + j] = f2h(v);
            }
        }
    } else {
        // Bpost: tile t = kt*4+nt (t = 0..31); this block packs 8 tiles.
        const int sub = threadIdx.x >> 5, s = threadIdx.x & 31;
        const int t = (pb - 1) * 8 + sub;
        const int kt = t >> 2, nt = t & 3;
#pragma unroll
        for (int e = 0; e < 16; ++e) {
            int idx = s * 16 + e;            // 0..511 within tile
            int l = idx >> 3, j = idx & 7;
            int rs = kt * 32 + ((l >> 4) & 3) * 8 + j;   // row of Wstack (0..255)
            int h = rs >> 6, k_in = rs & 63;
            int c = nt * 16 + (l & 15);
            Bpost[t * 512 + l * 8 + j] =
                f2h(loadW(isf32, W, k_in * 256 + h * 64 + c) * 0.25f);
        }
    }
}

// ---------------- logits + x->f16 from MFMA afrags (all k_mid blocks) --------
// Block = 64 rows, 4 waves; wave w: rows 16w..16w+15; single n-tile (Batt).
// C layout (HW-verified): col=lane&15, row=quad*4+reg. Cols 0..3 = a_src heads,
// 4..7 = a_dst heads (1/ln2-scaled) -> direct fp32 global writes.
// x16 is stored FROM the already-converted afrag registers.
template <typename T>
__device__ __forceinline__ void row_body(const T* __restrict__ x,
                                         const unsigned short* __restrict__ Batt,
                                         unsigned short* __restrict__ x16,
                                         float* __restrict__ a_src,
                                         float* __restrict__ a_dst) {
    const int tid = threadIdx.x;
    const int wav = tid >> 6, lane = tid & 63;
    const int quad = lane >> 4, r15 = lane & 15;
    const int m0 = blockIdx.x * 64;
    const int grow_a = m0 + wav * 16 + r15;     // this lane's A row (m = lane&15)
    int gr = grow_a;
    if (gr >= N_NODES) gr = N_NODES - 1;        // clamp; stores guarded
    half8 afrag[2];
#pragma unroll
    for (int q = 0; q < 2; ++q) {
        _Float16 tmp[8];
        load8_f16<T>(x + (size_t)gr * 64 + q * 32 + quad * 8, tmp);
#pragma unroll
        for (int j = 0; j < 8; ++j) afrag[q][j] = tmp[j];
    }
    // ---- f16 copy of x straight from registers (16B per store, full lines) -
    if (grow_a < N_NODES) {
#pragma unroll
        for (int q = 0; q < 2; ++q)
            *(half8*)(x16 + (size_t)grow_a * 64 + q * 32 + quad * 8) = afrag[q];
    }
    f32x4 acc = (f32x4){0.f, 0.f, 0.f, 0.f};
    const half8* bp = (const half8*)Batt;
    acc = __builtin_amdgcn_mfma_f32_16x16x32_f16(afrag[0], bp[lane], acc, 0, 0, 0);
    acc = __builtin_amdgcn_mfma_f32_16x16x32_f16(afrag[1], bp[64 + lane], acc, 0, 0, 0);
    if (r15 < 8) {
#pragma unroll
        for (int r = 0; r < 4; ++r) {
            int grow = m0 + wav * 16 + quad * 4 + r;
            if (grow < N_NODES) {
                if (r15 < 4) a_src[grow * HEADS + r15]       = acc[r];
                else         a_dst[grow * HEADS + (r15 - 4)] = acc[r];
            }
        }
    }
}

// ---------------- fused mid: rows + REGION-BUCKETED edge append -------------
// Even blocks bucket EPB=2048 edges into 391 region queues (region = dst>>7)
// as packed 4B records. Edge loads PAIRED (int4/int2) for full-line use.
// R11 post-mortem fix: qcnt is REPLICATED 8x (replica = eb&7) — before, each
// of 391 counters received 391 same-address device-scope atomics whose RMW
// chain (~75cy each) serialized ~12us on the critical path. Now ~49 adds per
// address (~2us, hidden under row_body). Queue = [region][replica][QSUB].
__global__ __launch_bounds__(256) void k_mid(const void* __restrict__ x,
                                             const unsigned short* __restrict__ Batt,
                                             const int* __restrict__ ei,
                                             const int* __restrict__ flags,
                                             int* __restrict__ qcnt,
                                             unsigned* __restrict__ queue,
                                             unsigned short* __restrict__ x16,
                                             float* __restrict__ a_src,
                                             float* __restrict__ a_dst) {
    __shared__ int hist[NREG];
    __shared__ int qbaseS[NREG];
    const int tid = threadIdx.x;
    const bool edge_blk = ((blockIdx.x & 1) == 0);   // interleaved for CU balance
    const int eb = blockIdx.x >> 1;                  // 0..390
    const int rep = eb & (NREP - 1);                 // my qcnt replica
    unsigned rec[8]; int reg[8], lpos[8];
    int histv0 = 0, histv1 = 0, mybase0 = 0, mybase1 = 0;
    if (edge_blk) {
        for (int t = tid; t < NREG; t += 256) hist[t] = 0;
        __syncthreads();
        const int f64 = flags[0];
        const int pbase = eb * 1024 + tid;           // pair index (2 edges/pair)
#pragma unroll
        for (int k = 0; k < 4; ++k) {
            int pid = pbase + k * 256;
            int e = 2 * pid;
            if (e < N_EDGES) {                       // N_EDGES even => e+1 valid
                int s0, d0, s1, d1;
                if (f64) {                           // 16B = 2 int64 edges
                    int4 sv = *(const int4*)(ei + 2 * e);
                    int4 dv = *(const int4*)(ei + 2 * N_EDGES + 2 * e);
                    s0 = sv.x; s1 = sv.z; d0 = dv.x; d1 = dv.z;
                } else {                             // 8B = 2 int32 edges
                    int2 sv = *(const int2*)(ei + e);
                    int2 dv = *(const int2*)(ei + N_EDGES + e);
                    s0 = sv.x; s1 = sv.y; d0 = dv.x; d1 = dv.y;
                }
                reg[2 * k]     = d0 >> 7;
                rec[2 * k]     = (unsigned)s0 | ((unsigned)d0 << 16);
                reg[2 * k + 1] = d1 >> 7;
                rec[2 * k + 1] = (unsigned)s1 | ((unsigned)d1 << 16);
            } else { reg[2 * k] = -1; reg[2 * k + 1] = -1; }
        }
#pragma unroll
        for (int k = 0; k < 8; ++k)
            if (reg[k] >= 0) lpos[k] = atomicAdd(&hist[reg[k]], 1);
        __syncthreads();
        {   // qcnt atomics issued BEFORE row_body (round trip hides under it)
            int t0 = tid, t1 = tid + 256;
            histv0 = hist[t0];
            if (histv0) mybase0 = atomicAdd(qcnt + rep * NREG + t0, histv0);
            if (t1 < NREG) {
                histv1 = hist[t1];
                if (histv1) mybase1 = atomicAdd(qcnt + rep * NREG + t1, histv1);
            }
        }
    }
    // ---- rows for ALL blocks ----
    if (flags[1]) row_body<float>((const float*)x, Batt, x16, a_src, a_dst);
    else          row_body<__hip_bfloat16>((const __hip_bfloat16*)x, Batt,
                                           x16, a_src, a_dst);
    if (edge_blk) {
        qbaseS[tid] = mybase0;
        if (tid + 256 < NREG) qbaseS[tid + 256] = mybase1;
        __syncthreads();
#pragma unroll
        for (int k = 0; k < 8; ++k)
            if (reg[k] >= 0) {
                int o = qbaseS[reg[k]] + lpos[k];
                if (o < QSUB)
                    queue[((size_t)reg[k] * NREP + rep) * QSUB + o] = rec[k];
            }
    }
}

// ---------------- scat: per-region 8 sub-queues -> col_pad (L2-local) -------
// One block per 128-node region (16 KB col_pad window, single-XCD L2).
// Positions via LDS atomics. Per-node count stored IN col_pad slot 63
// (self-loop occupies lane n <= 63, so slot 63 is never an edge slot).
__global__ __launch_bounds__(256) void k_scat(const unsigned* __restrict__ queue,
                                              const int* __restrict__ qcnt,
                                              unsigned short* __restrict__ col_pad) {
    __shared__ int cl[128];
    __shared__ int mr[NREP];
    const int b = blockIdx.x, tid = threadIdx.x;
    const int base = b << 7;
    if (tid < 128) cl[tid] = 0;
    if (tid < NREP) {
        int m = qcnt[tid * NREG + b];
        mr[tid] = m > QSUB ? QSUB : m;
    }
    __syncthreads();
#pragma unroll
    for (int rep = 0; rep < NREP; ++rep) {
        int m = mr[rep];
        const unsigned* q = queue + ((size_t)b * NREP + rep) * QSUB;
        for (int i = tid; i < m; i += 256) {
            unsigned rec = q[i];
            int d = rec >> 16, s = rec & 0xffff;
            int p = atomicAdd(&cl[d - base], 1);
            if (p < CAP - 1) col_pad[(size_t)d * CAP + p] = (unsigned short)s;
        }
    }
    __syncthreads();
    if (tid < 128) {
        int j = base + tid;
        if (j < N_NODES) {
            int c = cl[tid]; c = c > CAP - 1 ? CAP - 1 : c;
            col_pad[(size_t)j * CAP + (CAP - 1)] = (unsigned short)c;
        }
    }
}

// -------- fused aggregate+post (R10's v2u8 — best known, UNCHANGED) ---------
// 16 nodes/block, 256 thr / 4 waves, 4 serial nodes/wave; 2 edges/round with
// parity-interleaved col/pe lists; unroll-8; count from col_pad slot 63;
// phase 2: 16 staged rows = one MFMA M-tile, all 4 waves (wave = n-tile).
template <typename T>
__device__ __forceinline__ void agg_body(const unsigned short* __restrict__ col_pad,
                                         const float* __restrict__ a_src,
                                         const float* __restrict__ a_dst,
                                         const unsigned short* __restrict__ x16,
                                         const unsigned short* __restrict__ Bpost,
                                         const T* __restrict__ bias,
                                         const T* __restrict__ fc_w,
                                         const T* __restrict__ fc_b,
                                         float* __restrict__ out,
                                         int* __restrict__ cS,
                                         float4* __restrict__ peS,
                                         unsigned* __restrict__ sS,
                                         float* __restrict__ postS) {
    const int tid = threadIdx.x;
    const int wav = tid >> 6, lane = tid & 63;
    const int hlf = lane >> 5, l5 = lane & 31;
    const int quad = lane >> 4, r15 = lane & 15;
    const int nbase = blockIdx.x * 16 + wav * 4;            // 4 serial nodes/wave
    int* cSw = cS + wav * 64;
    float4* peSw = peS + wav * 64;
    const int slot = (lane & 1) * 32 + (lane >> 1);         // parity interleave
    const char* xb = (const char*)x16 + l5 * 4;             // my dim-pair slice
    int cval = (int)col_pad[(size_t)nbase * CAP + lane];    // node 0 row
#pragma unroll
    for (int nid = 0; nid < 4; ++nid) {
        const int wid = nbase + nid;
        int cval_next = 0;
        if (nid < 3)                                        // prefetch next row:
            cval_next = (int)col_pad[(size_t)(wid + 1) * CAP + lane];
        const int n = __shfl(cval, 63, 64);                 // count from slot 63
        const float4 ad = ((const float4*)a_dst)[wid];      // uniform
        const int mycol = (lane < n) ? cval : wid;          // lane n = self loop
        const float4 as = ((const float4*)a_src)[mycol];
        float e0 = as.x + ad.x, e1 = as.y + ad.y;
        float e2 = as.z + ad.z, e3 = as.w + ad.w;
        e0 = e0 > 0.f ? e0 : NEG_SLOPE * e0;  e1 = e1 > 0.f ? e1 : NEG_SLOPE * e1;
        e2 = e2 > 0.f ? e2 : NEG_SLOPE * e2;  e3 = e3 > 0.f ? e3 : NEG_SLOPE * e3;
        float4 pe = make_float4(exp2f(e0), exp2f(e1), exp2f(e2), exp2f(e3));
        if (lane > n) pe = make_float4(0.f, 0.f, 0.f, 0.f); // pad lanes
        cSw[slot] = mycol << 7;                             // x16 row BYTE offset
        peSw[slot] = pe;                                    // wave-sync (in-order DS)
        // ---- gather loop: per round, half h processes edge 2r+h ------------
        float a0 = 0.f, a1 = 0.f, a2 = 0.f, a3 = 0.f;       // a[h*2+t]
        float a4 = 0.f, a5 = 0.f, a6 = 0.f, a7 = 0.f;
        float sp0 = 0.f, sp1 = 0.f, sp2 = 0.f, sp3 = 0.f;   // my half's denom
        const int nr = (n + 2) >> 1;                        // rounds (n+1 entries)
        const int*    cB = cSw + hlf * 32;                  // my half's col list
        const float4* pB = peSw + hlf * 32;
#define ACC2(D, P) { float x0 = hbits((unsigned short)((D) & 0xffff)); \
                     float x1 = hbits((unsigned short)((D) >> 16)); \
                     a0 = fmaf((P).x, x0, a0); a1 = fmaf((P).x, x1, a1); \
                     a2 = fmaf((P).y, x0, a2); a3 = fmaf((P).y, x1, a3); \
                     a4 = fmaf((P).z, x0, a4); a5 = fmaf((P).z, x1, a5); \
                     a6 = fmaf((P).w, x0, a6); a7 = fmaf((P).w, x1, a7); \
                     sp0 += (P).x; sp1 += (P).y; sp2 += (P).z; sp3 += (P).w; }
        int r = 0;
        for (; r + 8 <= nr; r += 8) {                       // 16 loads in flight
            const int4 cc0 = *(const int4*)(cB + r);
            const int4 cc1 = *(const int4*)(cB + r + 4);
            unsigned dA = *(const unsigned*)(xb + cc0.x);
            unsigned dB = *(const unsigned*)(xb + cc0.y);
            unsigned dC = *(const unsigned*)(xb + cc0.z);
            unsigned dD = *(const unsigned*)(xb + cc0.w);
            unsigned dE = *(const unsigned*)(xb + cc1.x);
            unsigned dF = *(const unsigned*)(xb + cc1.y);
            unsigned dG = *(const unsigned*)(xb + cc1.z);
            unsigned dH = *(const unsigned*)(xb + cc1.w);
            float4 pA = pB[r],     pBv = pB[r + 1];
            float4 pC = pB[r + 2], pD  = pB[r + 3];
            float4 pE = pB[r + 4], pF  = pB[r + 5];
            float4 pG = pB[r + 6], pH  = pB[r + 7];
            ACC2(dA, pA); ACC2(dB, pBv); ACC2(dC, pC); ACC2(dD, pD);
            ACC2(dE, pE); ACC2(dF, pF);  ACC2(dG, pG); ACC2(dH, pH);
        }
        for (; r + 4 <= nr; r += 4) {
            const int4 cc = *(const int4*)(cB + r);
            unsigned dA = *(const unsigned*)(xb + cc.x);
            unsigned dB = *(const unsigned*)(xb + cc.y);
            unsigned dC = *(const unsigned*)(xb + cc.z);
            unsigned dD = *(const unsigned*)(xb + cc.w);
            float4 pA = pB[r], pBv = pB[r + 1], pC = pB[r + 2], pD = pB[r + 3];
            ACC2(dA, pA); ACC2(dB, pBv); ACC2(dC, pC); ACC2(dD, pD);
        }
        for (; r < nr; ++r) {
            int c = cB[r];
            unsigned d = *(const unsigned*)(xb + c);
            float4 p = pB[r];
            ACC2(d, p);
        }
#undef ACC2
        // ---- fold the two 32-lane halves (same dims, disjoint edges) -------
        a0 += __shfl_xor(a0, 32, 64); a1 += __shfl_xor(a1, 32, 64);
        a2 += __shfl_xor(a2, 32, 64); a3 += __shfl_xor(a3, 32, 64);
        a4 += __shfl_xor(a4, 32, 64); a5 += __shfl_xor(a5, 32, 64);
        a6 += __shfl_xor(a6, 32, 64); a7 += __shfl_xor(a7, 32, 64);
        sp0 += __shfl_xor(sp0, 32, 64); sp1 += __shfl_xor(sp1, 32, 64);
        sp2 += __shfl_xor(sp2, 32, 64); sp3 += __shfl_xor(sp3, 32, 64);
        const float r0 = 1.f / sp0, r1 = 1.f / sp1;
        const float r2 = 1.f / sp2, r3 = 1.f / sp3;
        // ---- normalize + stage s row into LDS (identical f2h packing) ------
        if (lane < 32) {
            unsigned* sr = sS + (wav * 4 + nid) * 132;      // pitch 132 dwords
            sr[l5]      = (unsigned)f2h(a0 * r0) | ((unsigned)f2h(a1 * r0) << 16);
            sr[32 + l5] = (unsigned)f2h(a2 * r1) | ((unsigned)f2h(a3 * r1) << 16);
            sr[64 + l5] = (unsigned)f2h(a4 * r2) | ((unsigned)f2h(a5 * r2) << 16);
            sr[96 + l5] = (unsigned)f2h(a6 * r3) | ((unsigned)f2h(a7 * r3) << 16);
        }
        cval = cval_next;
    }
    __syncthreads();
    // ---- post phase: ALL 4 waves, wave = n-tile nt --------------------------
    {
        const int nt = wav;
        f32x4 acc = (f32x4){0.f, 0.f, 0.f, 0.f};
        const half8* bp = (const half8*)Bpost;
#pragma unroll
        for (int kt = 0; kt < 8; ++kt) {
            half8 af = *(const half8*)&sS[r15 * 132 + kt * 16 + quad * 4];
            acc = __builtin_amdgcn_mfma_f32_16x16x32_f16(
                af, bp[(kt * 4 + nt) * 64 + lane], acc, 0, 0, 0);
        }
        const float bi = cvt<T>(bias[nt * 16 + r15]);
        const float fw = cvt<T>(fc_w[nt * 16 + r15]);
#pragma unroll
        for (int rr = 0; rr < 4; ++rr) {
            float o = acc[rr] + bi;
            o = o > 0.f ? o : 0.f;              // relu
            float p = o * fw;
            p += __shfl_xor(p, 1, 64); p += __shfl_xor(p, 2, 64);
            p += __shfl_xor(p, 4, 64); p += __shfl_xor(p, 8, 64);
            if (r15 == 0) postS[(quad * 4 + rr) * 4 + nt] = p;
        }
    }
    __syncthreads();
    if (tid < 16) {
        float o = postS[tid * 4] + postS[tid * 4 + 1]
                + postS[tid * 4 + 2] + postS[tid * 4 + 3] + cvt<T>(fc_b[0]);
        out[blockIdx.x * 16 + tid] = o;
    }
}

__global__ __launch_bounds__(256) void k_aggregate(
        const unsigned short* __restrict__ col_pad,
        const float* __restrict__ a_src,
        const float* __restrict__ a_dst,
        const unsigned short* __restrict__ x16,
        const unsigned short* __restrict__ Bpost,
        const void* __restrict__ bias,
        const void* __restrict__ fc_w,
        const void* __restrict__ fc_b,
        const int* __restrict__ flags,
        float* __restrict__ out) {
    __shared__ __align__(16) int cS[4 * 64];    // parity-interleaved col lists
    __shared__ float4 peS[4 * 64];
    __shared__ __align__(16) unsigned sS[16 * 132];  // staged s rows (f16 pairs)
    __shared__ float postS[16 * 4];
    if (flags[1])
        agg_body<float>(col_pad, a_src, a_dst, x16, Bpost, (const float*)bias,
                        (const float*)fc_w, (const float*)fc_b, out,
                        cS, peS, sS, postS);
    else
        agg_body<__hip_bfloat16>(col_pad, a_src, a_dst, x16, Bpost,
                                 (const __hip_bfloat16*)bias,
                                 (const __hip_bfloat16*)fc_w,
                                 (const __hip_bfloat16*)fc_b, out,
                                 cS, peS, sS, postS);
}

extern "C" void kernel_launch(void* const* d_in, const int* in_sizes, int n_in,
                              void* d_out, int out_size, void* d_ws, size_t ws_size,
                              hipStream_t stream) {
    const void* x       = d_in[0];
    const int*  ei      = (const int*)d_in[1];
    const void* W       = d_in[2];
    const void* att_src = d_in[3];
    const void* att_dst = d_in[4];
    const void* bias    = d_in[5];
    const void* fc_w    = d_in[6];
    const void* fc_b    = d_in[7];
    float* out = (float*)d_out;

    char* wsb = (char*)d_ws;                                      // ~19.3 MB total
    unsigned short* x16   = (unsigned short*)wsb;                 // 6.4 MB (f16 x)
    unsigned*       queue = (unsigned*)(wsb + 6400000);           // 4.8 MB (8 subQ)
    unsigned short* col_pad = (unsigned short*)(wsb + 11204608);  // 6.4 MB (128B-align)
    float* a_src = (float*)(wsb + 17604608);                      // 800 KB
    float* a_dst = (float*)(wsb + 18404608);                      // 800 KB
    unsigned short* Batt  = (unsigned short*)(wsb + 19204608);    // 2 KB
    unsigned short* Bpost = (unsigned short*)(wsb + 19206656);    // 32 KB
    int* flags = (int*)(wsb + 19239424);                          // 8 B
    int* qcnt  = (int*)(wsb + 19239432);                          // 12.5 KB (8xNREG)

    k_init<<<6, 256, 0, stream>>>((const unsigned*)x, ei, W, att_src,
                                  att_dst, qcnt, flags, Batt, Bpost);
    k_mid<<<NT, 256, 0, stream>>>(x, Batt, ei, flags, qcnt, queue,
                                  x16, a_src, a_dst);
    k_scat<<<NREG, 256, 0, stream>>>(queue, qcnt, col_pad);
    k_aggregate<<<NAGG, 256, 0, stream>>>(col_pad, a_src, a_dst, x16, Bpost,
                                          bias, fc_w, fc_b, flags, out);
}